// Round 5
// baseline (168.361 us; speedup 1.0000x reference)
//
#include <hip/hip_runtime.h>

#define IMG_H 4096
#define IMG_W 4096
#define RPT 4                 // rows per wave
#define WPR (IMG_W / 256)     // waves per row strip

typedef float floatx4 __attribute__((ext_vector_type(4)));
typedef int   intx4   __attribute__((ext_vector_type(4)));

// Bounds-checked buffer loads (MUBUF SRD): OOB lanes return 0.0 and never
// fault — this is what makes the shifted-load scheme safe at image borders.
// Volatile asm loads have a FIXED mutual order: all loads issue back-to-back,
// one vmcnt(0) wait, then pure VALU. The register allocator cannot
// re-serialize this the way it did to every HIP-level formulation (r1/r4:
// VGPR stuck at 32 = loads software-pipelined ~2 in flight).
__device__ __forceinline__ floatx4 bload(intx4 rsrc, int voff) {
    floatx4 d;
    asm volatile("buffer_load_dwordx4 %0, %1, %2, 0 offen"
                 : "=v"(d) : "v"(voff), "s"(rsrc));
    return d;
}
__device__ __forceinline__ floatx4 bload_nt(intx4 rsrc, int voff) {
    floatx4 d;
    asm volatile("buffer_load_dwordx4 %0, %1, %2, 0 offen nt"
                 : "=v"(d) : "v"(voff), "s"(rsrc));
    return d;
}

// Branch selection equivalent (verified bit-exact by boundary ulp-analysis) to:
//   q = rintf(deg/45.f)*45.f;  q==180 -> 0;  chain-compare 0/45/90/else.
__device__ __forceinline__ float nms_px(float t, bool interior,
                                        float uL, float uC, float uR,
                                        float cL, float cC, float cR,
                                        float dL, float dC, float dR) {
    float deg = t * 57.29577951308232f;        // float32(180/pi)
    deg = (deg < 0.0f) ? deg + 180.0f : deg;   // same fp32 add as reference
    const bool is0  = (deg >= -22.5f && deg <= 22.5f) || (deg >= 157.5f && deg <= 202.5f);
    const bool is45 = (deg >  22.5f) && (deg <  67.5f);
    const bool is90 = (deg >= 67.5f) && (deg <= 112.5f);
    const float a = is0 ? cR : (is45 ? dR : (is90 ? dC : dL));
    const float b = is0 ? cL : (is45 ? uL : (is90 ? uC : uR));
    return ((cC >= a) && (cC >= b) && interior) ? cC : 0.0f;
}

// One wave = 256 contiguous cols x RPT rows. Per img row k (x0-1+k), three
// 16B loads: aligned (a), shifted -1 float (m), +1 float (p). m[k][j] is px
// j's left neighbor, p[k][j] its right neighbor — no cross-lane shuffles,
// no edge-lane scalar loads, no LDS. Flat-buffer wraparound gives correct
// values everywhere except the image's own left/right columns:
//   - left col (lane y4==0): m comps 1..3 must come from a comps 0..2
//     (also covers the row-0 OOB-zero case); m comp0 feeds a masked px.
//   - right col (y4==IMG_W-4): p comps 0..2 from a comps 1..3 (covers the
//     last-row OOB-zero case); p comp3 feeds a masked px.
// Halo rows x=-1 / x=4096 are OOB -> zeros -> feed only masked rows 0/4095.
__global__ __launch_bounds__(256, 4) void nms_kernel(const float* __restrict__ img,
                                                     const float* __restrict__ theta,
                                                     float* __restrict__ out) {
    // XCD-aware remap: 4096 blocks, blk%8 = XCD -> 8 horizontal bands of 512 rows.
    const int xcd  = blockIdx.x & 7;
    const int slot = blockIdx.x >> 3;          // 0..511 within band
    const int g    = xcd * (IMG_H / RPT / 8) + (slot >> 2);   // row-group
    const int seg  = (slot & 3) * 4 + (threadIdx.x >> 6);     // col segment 0..15
    const int lane = threadIdx.x & 63;

    const int y4 = (seg << 8) + (lane << 2);   // this lane's 4-px chunk
    const int x0 = g * RPT;

    intx4 rimg, rth;
    rimg.x = (int)(uintptr_t)img;
    rimg.y = (int)(((uintptr_t)img) >> 32) & 0xFFFF;
    rimg.z = IMG_H * IMG_W * 4;                // num_records (bytes)
    rimg.w = 0x00020000;                       // raw dword SRD
    rth.x  = (int)(uintptr_t)theta;
    rth.y  = (int)(((uintptr_t)theta) >> 32) & 0xFFFF;
    rth.z  = IMG_H * IMG_W * 4;
    rth.w  = 0x00020000;

    floatx4 a[RPT + 2], m[RPT + 2], p[RPT + 2], th[RPT];

    // ---- issue ALL loads back-to-back (theta first: HBM, longest latency) ----
    #pragma unroll
    for (int i = 0; i < RPT; ++i)
        th[i] = bload_nt(rth, ((x0 + i) * IMG_W + y4) * 4);

    const int base = ((x0 - 1) * IMG_W + y4) * 4;  // byte offset, row x0-1
    #pragma unroll
    for (int k = 0; k < RPT + 2; ++k) {
        const int ro = base + k * (IMG_W * 4);
        a[k] = bload(rimg, ro);
        m[k] = bload(rimg, ro - 4);
        p[k] = bload(rimg, ro + 4);
    }

    // ---- single wait; sched_barrier stops hipcc hoisting uses above it ----
    asm volatile("s_waitcnt vmcnt(0)" ::: "memory");
    __builtin_amdgcn_sched_barrier(0);

    // ---- border-column component fixes (2 lanes per wave-row at most) ----
    const bool eL = (y4 == 0);
    const bool eR = (y4 == IMG_W - 4);
    #pragma unroll
    for (int k = 0; k < RPT + 2; ++k) {
        m[k].y = eL ? a[k].x : m[k].y;
        m[k].z = eL ? a[k].y : m[k].z;
        m[k].w = eL ? a[k].z : m[k].w;
        p[k].x = eR ? a[k].y : p[k].x;
        p[k].y = eR ? a[k].z : p[k].y;
        p[k].z = eR ? a[k].w : p[k].z;
    }

    const bool c0_int = (y4 > 0);
    const bool c3_int = (y4 + 4 < IMG_W);

    // ---- pure-VALU compute + NT stores ----
    #pragma unroll
    for (int i = 0; i < RPT; ++i) {
        const int x = x0 + i;
        const bool row_int = (x > 0) && (x < IMG_H - 1);
        const floatx4 t = th[i];

        floatx4 o;
        o.x = nms_px(t.x, row_int && c0_int,
                     m[i].x, a[i].x, p[i].x,
                     m[i+1].x, a[i+1].x, p[i+1].x,
                     m[i+2].x, a[i+2].x, p[i+2].x);
        o.y = nms_px(t.y, row_int,
                     m[i].y, a[i].y, p[i].y,
                     m[i+1].y, a[i+1].y, p[i+1].y,
                     m[i+2].y, a[i+2].y, p[i+2].y);
        o.z = nms_px(t.z, row_int,
                     m[i].z, a[i].z, p[i].z,
                     m[i+1].z, a[i+1].z, p[i+1].z,
                     m[i+2].z, a[i+2].z, p[i+2].z);
        o.w = nms_px(t.w, row_int && c3_int,
                     m[i].w, a[i].w, p[i].w,
                     m[i+1].w, a[i+1].w, p[i+1].w,
                     m[i+2].w, a[i+2].w, p[i+2].w);

        floatx4* po = (floatx4*)(out + (size_t)x * IMG_W + y4);
        __builtin_nontemporal_store(o, po);
    }
}

extern "C" void kernel_launch(void* const* d_in, const int* in_sizes, int n_in,
                              void* d_out, int out_size, void* d_ws, size_t ws_size,
                              hipStream_t stream) {
    const float* img   = (const float*)d_in[0];
    const float* theta = (const float*)d_in[1];
    float* out = (float*)d_out;

    const int total_threads = (IMG_H / RPT) * WPR * 64;  // 1024 * 16 * 64
    const int block = 256;
    const int grid = total_threads / block;               // 4096
    nms_kernel<<<grid, block, 0, stream>>>(img, theta, out);
}